// Round 1
// baseline (1194.142 us; speedup 1.0000x reference)
//
#include <hip/hip_runtime.h>

// ---------------- CSR build ----------------

__global__ void hist_kernel(const int* __restrict__ ei, int* __restrict__ cnt, int E) {
    for (int e = blockIdx.x * blockDim.x + threadIdx.x; e < E; e += gridDim.x * blockDim.x) {
        atomicAdd(&cnt[ei[E + e]], 1);   // dst row
    }
}

__global__ void dinv_kernel(const int* __restrict__ cnt, float* __restrict__ dinv, int n) {
    int i = blockIdx.x * blockDim.x + threadIdx.x;
    if (i < n) dinv[i] = rsqrtf((float)(cnt[i] + 1));  // +1 = self-loop
}

// exclusive scan of cnt[n] -> offs, 3-kernel (tile = 4096 = 256 thr * 16)
__global__ void scan1_kernel(const int* __restrict__ cnt, int* __restrict__ offs,
                             int* __restrict__ bsums, int n) {
    __shared__ int s[256];
    int t = threadIdx.x;
    int base = blockIdx.x * 4096 + t * 16;
    int vals[16];
    int sum = 0;
#pragma unroll
    for (int j = 0; j < 16; ++j) {
        int idx = base + j;
        int v = (idx < n) ? cnt[idx] : 0;
        vals[j] = v; sum += v;
    }
    s[t] = sum;
    __syncthreads();
    for (int off = 1; off < 256; off <<= 1) {
        int v = (t >= off) ? s[t - off] : 0;
        __syncthreads();
        s[t] += v;
        __syncthreads();
    }
    int run = s[t] - sum;            // exclusive base for this thread
    if (t == 255) bsums[blockIdx.x] = s[255];
#pragma unroll
    for (int j = 0; j < 16; ++j) {
        int idx = base + j;
        if (idx < n) offs[idx] = run;
        run += vals[j];
    }
}

__global__ void scan2_kernel(int* __restrict__ bsums, int* __restrict__ offs, int nb, int n) {
    if (blockIdx.x == 0 && threadIdx.x == 0) {
        int run = 0;
        for (int b = 0; b < nb; ++b) { int v = bsums[b]; bsums[b] = run; run += v; }
        offs[n] = run;   // == E
    }
}

__global__ void scan3_kernel(const int* __restrict__ bsums, int* __restrict__ offs,
                             int* __restrict__ cursor, int n) {
    int i = blockIdx.x * blockDim.x + threadIdx.x;
    if (i < n) {
        int o = offs[i] + bsums[i >> 12];
        offs[i] = o;
        cursor[i] = o;
    }
}

__global__ void scatter_kernel(const int* __restrict__ ei, int* __restrict__ cursor,
                               int* __restrict__ srt, int E) {
    for (int e = blockIdx.x * blockDim.x + threadIdx.x; e < E; e += gridDim.x * blockDim.x) {
        int v = ei[E + e];                       // dst
        int p = atomicAdd(&cursor[v], 1);
        srt[p] = ei[e];                          // src
    }
}

// ---------------- GEMM (fp32) fused with dinv row-scale: G = (X@W) * dinv[row] ----------------
// X: [n, K], W: [K, 128], G: [n, 128]. 64-row x 128-col tile per block, 256 threads.
template <int K>
__global__ __launch_bounds__(256) void gemm_scale(const float* __restrict__ X,
                                                  const float* __restrict__ W,
                                                  const float* __restrict__ dinv,
                                                  float* __restrict__ G, int n) {
    __shared__ float xs[64][36];    // [row][k], padded to keep 16B align + spread banks
    __shared__ float ws[32][128];   // [k][col]
    const int tid = threadIdx.x;
    const int row0 = blockIdx.x * 64;
    const int tc = tid & 31;        // col quad id (cols 4*tc..4*tc+3)
    const int tr = tid >> 5;        // 0..7 (rows tr, tr+8, ..., tr+56)
    const int lr = tid >> 3;        // 0..31 loader row
    const int lk = (tid & 7) * 4;   // loader k quad
    const int wc = (tid & 31) * 4;  // W loader col
    const int wk = tid >> 5;        // W loader k row (0..7)

    float acc[8][4];
#pragma unroll
    for (int i = 0; i < 8; ++i)
#pragma unroll
        for (int j = 0; j < 4; ++j) acc[i][j] = 0.f;

    for (int k0 = 0; k0 < K; k0 += 32) {
        __syncthreads();
#pragma unroll
        for (int h = 0; h < 2; ++h) {
            int r = lr + 32 * h;
            int grow = row0 + r;
            float4 v = make_float4(0.f, 0.f, 0.f, 0.f);
            if (grow < n) v = *(const float4*)&X[(size_t)grow * K + k0 + lk];
            *(float4*)&xs[r][lk] = v;
        }
#pragma unroll
        for (int p = 0; p < 4; ++p) {
            int kr = wk + 8 * p;
            float4 v = *(const float4*)&W[(size_t)(k0 + kr) * 128 + wc];
            *(float4*)&ws[kr][wc] = v;
        }
        __syncthreads();
#pragma unroll
        for (int k = 0; k < 32; ++k) {
            float4 wv = *(const float4*)&ws[k][tc * 4];
#pragma unroll
            for (int i = 0; i < 8; ++i) {
                float xv = xs[tr + 8 * i][k];
                acc[i][0] += xv * wv.x;
                acc[i][1] += xv * wv.y;
                acc[i][2] += xv * wv.z;
                acc[i][3] += xv * wv.w;
            }
        }
    }
#pragma unroll
    for (int i = 0; i < 8; ++i) {
        int grow = row0 + tr + 8 * i;
        if (grow < n) {
            float dv = dinv[grow];
            float4 o = make_float4(acc[i][0] * dv, acc[i][1] * dv, acc[i][2] * dv, acc[i][3] * dv);
            *(float4*)&G[(size_t)grow * 128 + tc * 4] = o;
        }
    }
}

// ---------------- Aggregation: H[v] = relu?(dinv[v]*(sum_{e in CSR[v]} G[src] + G[v]) + b) ----
// one wave (64 lanes) per node; lane covers 2 of 128 channels
__global__ __launch_bounds__(256) void aggregate_kernel(const float* __restrict__ G,
                                                        const int* __restrict__ offs,
                                                        const int* __restrict__ srt,
                                                        const float* __restrict__ dinv,
                                                        const float* __restrict__ bias,
                                                        float* __restrict__ H, int n, int do_relu) {
    int wid = (blockIdx.x * blockDim.x + threadIdx.x) >> 6;
    int lane = threadIdx.x & 63;
    if (wid >= n) return;
    int beg = offs[wid], end = offs[wid + 1];
    int c = lane * 2;
    float2 self = *(const float2*)&G[(size_t)wid * 128 + c];
    float ax = self.x, ay = self.y;
    int e = beg;
    for (; e + 4 <= end; e += 4) {
        int s0 = srt[e], s1 = srt[e + 1], s2 = srt[e + 2], s3 = srt[e + 3];
        float2 v0 = *(const float2*)&G[(size_t)s0 * 128 + c];
        float2 v1 = *(const float2*)&G[(size_t)s1 * 128 + c];
        float2 v2 = *(const float2*)&G[(size_t)s2 * 128 + c];
        float2 v3 = *(const float2*)&G[(size_t)s3 * 128 + c];
        ax += v0.x + v1.x + v2.x + v3.x;
        ay += v0.y + v1.y + v2.y + v3.y;
    }
    for (; e < end; ++e) {
        int s = srt[e];
        float2 v = *(const float2*)&G[(size_t)s * 128 + c];
        ax += v.x; ay += v.y;
    }
    float dv = dinv[wid];
    float r0 = ax * dv + bias[c];
    float r1 = ay * dv + bias[c + 1];
    if (do_relu) { r0 = fmaxf(r0, 0.f); r1 = fmaxf(r1, 0.f); }
    *(float2*)&H[(size_t)wid * 128 + c] = make_float2(r0, r1);
}

// ---------------- Layer-3 tiny GEMM: G3[v] = (H[v] @ Wc) * dinv[v], Wc: [128,2] ----------------
__global__ __launch_bounds__(256) void gemm_c2_kernel(const float* __restrict__ H,
                                                      const float* __restrict__ Wc,
                                                      const float* __restrict__ dinv,
                                                      float* __restrict__ G3, int n) {
    int wid = (blockIdx.x * blockDim.x + threadIdx.x) >> 6;
    int lane = threadIdx.x & 63;
    if (wid >= n) return;
    float2 h = *(const float2*)&H[(size_t)wid * 128 + lane * 2];
    float w00 = Wc[lane * 4 + 0];  // row 2*lane,   col 0
    float w01 = Wc[lane * 4 + 1];  // row 2*lane,   col 1
    float w10 = Wc[lane * 4 + 2];  // row 2*lane+1, col 0
    float w11 = Wc[lane * 4 + 3];  // row 2*lane+1, col 1
    float p0 = h.x * w00 + h.y * w10;
    float p1 = h.x * w01 + h.y * w11;
    for (int off = 32; off > 0; off >>= 1) {
        p0 += __shfl_xor(p0, off);
        p1 += __shfl_xor(p1, off);
    }
    if (lane == 0) {
        float dv = dinv[wid];
        G3[(size_t)wid * 2 + 0] = p0 * dv;
        G3[(size_t)wid * 2 + 1] = p1 * dv;
    }
}

// ---------------- Final: out[i] = dinv[v]*(sum g3[src] + g3[v]) + bc, v = ptr[i] ----------------
__global__ __launch_bounds__(64) void final_kernel(const float* __restrict__ G3,
                                                   const int* __restrict__ ptr,
                                                   const int* __restrict__ offs,
                                                   const int* __restrict__ srt,
                                                   const float* __restrict__ dinv,
                                                   const float* __restrict__ bc,
                                                   float* __restrict__ out, int ngraphs) {
    int i = blockIdx.x;
    if (i >= ngraphs) return;
    int v = ptr[i];
    int lane = threadIdx.x;
    float p0 = 0.f, p1 = 0.f;
    int beg = offs[v], end = offs[v + 1];
    for (int e = beg + lane; e < end; e += 64) {
        int s = srt[e];
        p0 += G3[(size_t)s * 2 + 0];
        p1 += G3[(size_t)s * 2 + 1];
    }
    for (int off = 32; off > 0; off >>= 1) {
        p0 += __shfl_xor(p0, off);
        p1 += __shfl_xor(p1, off);
    }
    if (lane == 0) {
        p0 += G3[(size_t)v * 2 + 0];
        p1 += G3[(size_t)v * 2 + 1];
        float dv = dinv[v];
        out[i * 2 + 0] = p0 * dv + bc[0];
        out[i * 2 + 1] = p1 * dv + bc[1];
    }
}

extern "C" void kernel_launch(void* const* d_in, const int* in_sizes, int n_in,
                              void* d_out, int out_size, void* d_ws, size_t ws_size,
                              hipStream_t stream) {
    const float* x  = (const float*)d_in[0];
    const int* ei   = (const int*)d_in[1];   // [2, E] int32
    const int* ptr  = (const int*)d_in[2];   // [NG+1] int32
    const float* W1 = (const float*)d_in[3];
    const float* b1 = (const float*)d_in[4];
    const float* W2 = (const float*)d_in[5];
    const float* b2 = (const float*)d_in[6];
    const float* Wc = (const float*)d_in[7];
    const float* bc = (const float*)d_in[8];
    float* out = (float*)d_out;

    const int IN_DIM = 768, HID = 128;
    const int NN = in_sizes[0] / IN_DIM;     // 100000
    const int E  = in_sizes[1] / 2;          // 3200000
    const int NG = in_sizes[2] - 1;          // 512

    char* ws = (char*)d_ws;
    size_t off = 0;
    auto alloc = [&](size_t bytes) -> void* {
        void* p = ws + off;
        off += (bytes + 255) & ~(size_t)255;
        return p;
    };
    int*   cnt    = (int*)alloc((size_t)NN * 4);
    float* dinv   = (float*)alloc((size_t)NN * 4);
    int*   offs   = (int*)alloc((size_t)(NN + 1) * 4);
    int*   cursor = (int*)alloc((size_t)NN * 4);
    int*   bsums  = (int*)alloc(4096);
    int*   srt    = (int*)alloc((size_t)E * 4);
    float* G      = (float*)alloc((size_t)NN * HID * 4);
    float* H      = (float*)alloc((size_t)NN * HID * 4);
    float* G3     = (float*)alloc((size_t)NN * 2 * 4);

    (void)n_in; (void)out_size; (void)ws_size;

    hipMemsetAsync(cnt, 0, (size_t)NN * 4, stream);
    hist_kernel<<<2048, 256, 0, stream>>>(ei, cnt, E);
    dinv_kernel<<<(NN + 255) / 256, 256, 0, stream>>>(cnt, dinv, NN);

    int nb = (NN + 4095) / 4096;
    scan1_kernel<<<nb, 256, 0, stream>>>(cnt, offs, bsums, NN);
    scan2_kernel<<<1, 64, 0, stream>>>(bsums, offs, nb, NN);
    scan3_kernel<<<(NN + 255) / 256, 256, 0, stream>>>(bsums, offs, cursor, NN);
    scatter_kernel<<<2048, 256, 0, stream>>>(ei, cursor, srt, E);

    int gemm_blocks = (NN + 63) / 64;
    int agg_blocks = (NN * 64 + 255) / 256;

    // layer 1
    gemm_scale<768><<<gemm_blocks, 256, 0, stream>>>(x, W1, dinv, G, NN);
    aggregate_kernel<<<agg_blocks, 256, 0, stream>>>(G, offs, srt, dinv, b1, H, NN, 1);
    // layer 2
    gemm_scale<128><<<gemm_blocks, 256, 0, stream>>>(H, W2, dinv, G, NN);
    aggregate_kernel<<<agg_blocks, 256, 0, stream>>>(G, offs, srt, dinv, b2, H, NN, 1);
    // layer 3 (only 512 output nodes need aggregation)
    gemm_c2_kernel<<<agg_blocks, 256, 0, stream>>>(H, Wc, dinv, G3, NN);
    final_kernel<<<NG, 64, 0, stream>>>(G3, ptr, offs, srt, dinv, bc, out, NG);
}

// Round 2
// 936.294 us; speedup vs baseline: 1.2754x; 1.2754x over previous
//
#include <hip/hip_runtime.h>

typedef short bf16x8 __attribute__((ext_vector_type(8)));
typedef float f32x4 __attribute__((ext_vector_type(4)));

__device__ __forceinline__ unsigned short f2bf_rn(float x) {
    unsigned int u = __float_as_uint(x);
    unsigned int r = u + 0x7FFF + ((u >> 16) & 1);
    return (unsigned short)(r >> 16);
}
__device__ __forceinline__ float bf2f(unsigned short h) {
    return __uint_as_float(((unsigned int)h) << 16);
}

// ---------------- CSR build ----------------

__global__ void hist_kernel(const int* __restrict__ ei, int* __restrict__ cnt, int E) {
    for (int e = blockIdx.x * blockDim.x + threadIdx.x; e < E; e += gridDim.x * blockDim.x) {
        atomicAdd(&cnt[ei[E + e]], 1);   // dst row
    }
}

__global__ void dinv_kernel(const int* __restrict__ cnt, float* __restrict__ dinv, int n) {
    int i = blockIdx.x * blockDim.x + threadIdx.x;
    if (i < n) dinv[i] = rsqrtf((float)(cnt[i] + 1));  // +1 = self-loop
}

__global__ void scan1_kernel(const int* __restrict__ cnt, int* __restrict__ offs,
                             int* __restrict__ bsums, int n) {
    __shared__ int s[256];
    int t = threadIdx.x;
    int base = blockIdx.x * 4096 + t * 16;
    int vals[16];
    int sum = 0;
#pragma unroll
    for (int j = 0; j < 16; ++j) {
        int idx = base + j;
        int v = (idx < n) ? cnt[idx] : 0;
        vals[j] = v; sum += v;
    }
    s[t] = sum;
    __syncthreads();
    for (int off = 1; off < 256; off <<= 1) {
        int v = (t >= off) ? s[t - off] : 0;
        __syncthreads();
        s[t] += v;
        __syncthreads();
    }
    int run = s[t] - sum;
    if (t == 255) bsums[blockIdx.x] = s[255];
#pragma unroll
    for (int j = 0; j < 16; ++j) {
        int idx = base + j;
        if (idx < n) offs[idx] = run;
        run += vals[j];
    }
}

__global__ void scan2_kernel(int* __restrict__ bsums, int* __restrict__ offs, int nb, int n) {
    if (blockIdx.x == 0 && threadIdx.x == 0) {
        int run = 0;
        for (int b = 0; b < nb; ++b) { int v = bsums[b]; bsums[b] = run; run += v; }
        offs[n] = run;
    }
}

__global__ void scan3_kernel(const int* __restrict__ bsums, int* __restrict__ offs,
                             int* __restrict__ cursor, int n) {
    int i = blockIdx.x * blockDim.x + threadIdx.x;
    if (i < n) {
        int o = offs[i] + bsums[i >> 12];
        offs[i] = o;
        cursor[i] = o;
    }
}

__global__ void scatter_kernel(const int* __restrict__ ei, int* __restrict__ cursor,
                               int* __restrict__ srt, int E) {
    for (int e = blockIdx.x * blockDim.x + threadIdx.x; e < E; e += gridDim.x * blockDim.x) {
        int v = ei[E + e];
        int p = atomicAdd(&cursor[v], 1);
        srt[p] = ei[e];
    }
}

// ---------------- W pre-split: W[K][128] fp32 -> Wt_hi/Wt_lo[col][K] bf16 ----------------
__global__ void wt_prep(const float* __restrict__ W, unsigned short* __restrict__ hi,
                        unsigned short* __restrict__ lo, int K) {
    int idx = blockIdx.x * 256 + threadIdx.x;
    if (idx >= K * 128) return;
    int k = idx >> 7;
    int c = idx & 127;
    float x = W[idx];
    unsigned short h = f2bf_rn(x);
    unsigned short l = f2bf_rn(x - bf2f(h));
    hi[(size_t)c * K + k] = h;
    lo[(size_t)c * K + k] = l;
}

// ---------------- MFMA GEMM (split-bf16): G = (X@W) * dinv[row] ----------------
// X: [n,K] fp32. Wt_hi/lo: [128][K] bf16 (W transposed, split). G: [n,128] fp32.
// Block: 256 thr (4 waves), tile 128 rows x 128 cols, BK=32.
template <int K>
__global__ __launch_bounds__(256) void gemm_mfma(const float* __restrict__ X,
                                                 const unsigned short* __restrict__ Wt_hi,
                                                 const unsigned short* __restrict__ Wt_lo,
                                                 const float* __restrict__ dinv,
                                                 float* __restrict__ G, int n) {
    __shared__ unsigned short As_hi[128][40];
    __shared__ unsigned short As_lo[128][40];
    __shared__ unsigned short Bs_hi[128][40];
    __shared__ unsigned short Bs_lo[128][40];

    const int tid = threadIdx.x;
    const int wave = tid >> 6;
    const int lane = tid & 63;
    const int l15 = lane & 15;
    const int l4 = lane >> 4;          // 0..3 (k-octet)
    const int row0 = blockIdx.x * 128;
    const int wr0 = wave * 32;

    f32x4 acc[2][8];
#pragma unroll
    for (int i = 0; i < 2; ++i)
#pragma unroll
        for (int j = 0; j < 8; ++j) acc[i][j] = (f32x4){0.f, 0.f, 0.f, 0.f};

    // staging indices
    const int sr = tid >> 1;           // 0..127 row
    const int sf = (tid & 1) * 16;     // float offset within 32-k chunk

    for (int k0 = 0; k0 < K; k0 += 32) {
        __syncthreads();
        // --- stage X tile (128 x 32 fp32), split to hi/lo bf16 ---
        {
            int grow = row0 + sr;
            float4 v[4];
            if (grow < n) {
                const float* src = X + (size_t)grow * K + k0 + sf;
#pragma unroll
                for (int g = 0; g < 4; ++g) v[g] = *(const float4*)(src + g * 4);
            } else {
#pragma unroll
                for (int g = 0; g < 4; ++g) v[g] = make_float4(0.f, 0.f, 0.f, 0.f);
            }
#pragma unroll
            for (int g = 0; g < 4; ++g) {
                ushort4 h, l;
                h.x = f2bf_rn(v[g].x); l.x = f2bf_rn(v[g].x - bf2f(h.x));
                h.y = f2bf_rn(v[g].y); l.y = f2bf_rn(v[g].y - bf2f(h.y));
                h.z = f2bf_rn(v[g].z); l.z = f2bf_rn(v[g].z - bf2f(h.z));
                h.w = f2bf_rn(v[g].w); l.w = f2bf_rn(v[g].w - bf2f(h.w));
                *(ushort4*)&As_hi[sr][sf + g * 4] = h;
                *(ushort4*)&As_lo[sr][sf + g * 4] = l;
            }
        }
        // --- stage B tile: 128 cols x 32 k bf16, straight 16B copies ---
        {
#pragma unroll
            for (int rep = 0; rep < 2; ++rep) {
                int id = tid + rep * 256;     // 0..511
                int c = id >> 2;
                int q = (id & 3) * 8;
                *(uint4*)&Bs_hi[c][q] = *(const uint4*)&Wt_hi[(size_t)c * K + k0 + q];
                *(uint4*)&Bs_lo[c][q] = *(const uint4*)&Wt_lo[(size_t)c * K + k0 + q];
            }
        }
        __syncthreads();
        // --- compute: 48 mfma per wave ---
        bf16x8 ah[2], al[2];
#pragma unroll
        for (int i = 0; i < 2; ++i) {
            ah[i] = *(const bf16x8*)&As_hi[wr0 + i * 16 + l15][l4 * 8];
            al[i] = *(const bf16x8*)&As_lo[wr0 + i * 16 + l15][l4 * 8];
        }
#pragma unroll
        for (int j = 0; j < 8; ++j) {
            bf16x8 bh = *(const bf16x8*)&Bs_hi[j * 16 + l15][l4 * 8];
            bf16x8 bl = *(const bf16x8*)&Bs_lo[j * 16 + l15][l4 * 8];
#pragma unroll
            for (int i = 0; i < 2; ++i) {
                acc[i][j] = __builtin_amdgcn_mfma_f32_16x16x32_bf16(ah[i], bh, acc[i][j], 0, 0, 0);
                acc[i][j] = __builtin_amdgcn_mfma_f32_16x16x32_bf16(ah[i], bl, acc[i][j], 0, 0, 0);
                acc[i][j] = __builtin_amdgcn_mfma_f32_16x16x32_bf16(al[i], bh, acc[i][j], 0, 0, 0);
            }
        }
    }
    // --- epilogue: C/D layout col=lane&15, row=(lane>>4)*4+r ---
#pragma unroll
    for (int i = 0; i < 2; ++i) {
#pragma unroll
        for (int r = 0; r < 4; ++r) {
            int grow = row0 + wr0 + i * 16 + l4 * 4 + r;
            if (grow < n) {
                float dv = dinv[grow];
#pragma unroll
                for (int j = 0; j < 8; ++j) {
                    G[(size_t)grow * 128 + j * 16 + l15] = acc[i][j][r] * dv;
                }
            }
        }
    }
}

// ---------------- Aggregation: H[v] = relu?(dinv[v]*(sum G[src] + G[v]) + b) ----------------
// one wave per node; half-wave per edge, lane covers 4 channels (float4)
__global__ __launch_bounds__(256) void aggregate_kernel(const float* __restrict__ G,
                                                        const int* __restrict__ offs,
                                                        const int* __restrict__ srt,
                                                        const float* __restrict__ dinv,
                                                        const float* __restrict__ bias,
                                                        float* __restrict__ H, int n, int do_relu) {
    int wid = (blockIdx.x * blockDim.x + threadIdx.x) >> 6;
    int lane = threadIdx.x & 63;
    if (wid >= n) return;
    int hh = lane >> 5;                 // half-wave id
    int c4 = (lane & 31) * 4;
    int beg = offs[wid], end = offs[wid + 1];
    float4 a = make_float4(0.f, 0.f, 0.f, 0.f);
    if (!hh) a = *(const float4*)&G[(size_t)wid * 128 + c4];   // self-loop term
    int e = beg + hh;
    for (; e + 6 < end; e += 8) {
        int s0 = srt[e], s1 = srt[e + 2], s2 = srt[e + 4], s3 = srt[e + 6];
        float4 v0 = *(const float4*)&G[(size_t)s0 * 128 + c4];
        float4 v1 = *(const float4*)&G[(size_t)s1 * 128 + c4];
        float4 v2 = *(const float4*)&G[(size_t)s2 * 128 + c4];
        float4 v3 = *(const float4*)&G[(size_t)s3 * 128 + c4];
        a.x += v0.x + v1.x + v2.x + v3.x;
        a.y += v0.y + v1.y + v2.y + v3.y;
        a.z += v0.z + v1.z + v2.z + v3.z;
        a.w += v0.w + v1.w + v2.w + v3.w;
    }
    for (; e < end; e += 2) {
        int s = srt[e];
        float4 v = *(const float4*)&G[(size_t)s * 128 + c4];
        a.x += v.x; a.y += v.y; a.z += v.z; a.w += v.w;
    }
    a.x += __shfl_xor(a.x, 32);
    a.y += __shfl_xor(a.y, 32);
    a.z += __shfl_xor(a.z, 32);
    a.w += __shfl_xor(a.w, 32);
    if (!hh) {
        float dv = dinv[wid];
        float4 b = *(const float4*)&bias[c4];
        float4 r;
        r.x = a.x * dv + b.x;
        r.y = a.y * dv + b.y;
        r.z = a.z * dv + b.z;
        r.w = a.w * dv + b.w;
        if (do_relu) {
            r.x = fmaxf(r.x, 0.f); r.y = fmaxf(r.y, 0.f);
            r.z = fmaxf(r.z, 0.f); r.w = fmaxf(r.w, 0.f);
        }
        *(float4*)&H[(size_t)wid * 128 + c4] = r;
    }
}

// ---------------- Layer-3 tiny GEMM: G3[v] = (H[v] @ Wc) * dinv[v] ----------------
__global__ __launch_bounds__(256) void gemm_c2_kernel(const float* __restrict__ H,
                                                      const float* __restrict__ Wc,
                                                      const float* __restrict__ dinv,
                                                      float* __restrict__ G3, int n) {
    int wid = (blockIdx.x * blockDim.x + threadIdx.x) >> 6;
    int lane = threadIdx.x & 63;
    if (wid >= n) return;
    float2 h = *(const float2*)&H[(size_t)wid * 128 + lane * 2];
    float w00 = Wc[lane * 4 + 0];
    float w01 = Wc[lane * 4 + 1];
    float w10 = Wc[lane * 4 + 2];
    float w11 = Wc[lane * 4 + 3];
    float p0 = h.x * w00 + h.y * w10;
    float p1 = h.x * w01 + h.y * w11;
    for (int off = 32; off > 0; off >>= 1) {
        p0 += __shfl_xor(p0, off);
        p1 += __shfl_xor(p1, off);
    }
    if (lane == 0) {
        float dv = dinv[wid];
        G3[(size_t)wid * 2 + 0] = p0 * dv;
        G3[(size_t)wid * 2 + 1] = p1 * dv;
    }
}

__global__ __launch_bounds__(64) void final_kernel(const float* __restrict__ G3,
                                                   const int* __restrict__ ptr,
                                                   const int* __restrict__ offs,
                                                   const int* __restrict__ srt,
                                                   const float* __restrict__ dinv,
                                                   const float* __restrict__ bc,
                                                   float* __restrict__ out, int ngraphs) {
    int i = blockIdx.x;
    if (i >= ngraphs) return;
    int v = ptr[i];
    int lane = threadIdx.x;
    float p0 = 0.f, p1 = 0.f;
    int beg = offs[v], end = offs[v + 1];
    for (int e = beg + lane; e < end; e += 64) {
        int s = srt[e];
        p0 += G3[(size_t)s * 2 + 0];
        p1 += G3[(size_t)s * 2 + 1];
    }
    for (int off = 32; off > 0; off >>= 1) {
        p0 += __shfl_xor(p0, off);
        p1 += __shfl_xor(p1, off);
    }
    if (lane == 0) {
        p0 += G3[(size_t)v * 2 + 0];
        p1 += G3[(size_t)v * 2 + 1];
        float dv = dinv[v];
        out[i * 2 + 0] = p0 * dv + bc[0];
        out[i * 2 + 1] = p1 * dv + bc[1];
    }
}

extern "C" void kernel_launch(void* const* d_in, const int* in_sizes, int n_in,
                              void* d_out, int out_size, void* d_ws, size_t ws_size,
                              hipStream_t stream) {
    const float* x  = (const float*)d_in[0];
    const int* ei   = (const int*)d_in[1];
    const int* ptr  = (const int*)d_in[2];
    const float* W1 = (const float*)d_in[3];
    const float* b1 = (const float*)d_in[4];
    const float* W2 = (const float*)d_in[5];
    const float* b2 = (const float*)d_in[6];
    const float* Wc = (const float*)d_in[7];
    const float* bc = (const float*)d_in[8];
    float* out = (float*)d_out;

    const int IN_DIM = 768, HID = 128;
    const int NN = in_sizes[0] / IN_DIM;     // 100000
    const int E  = in_sizes[1] / 2;          // 3200000
    const int NG = in_sizes[2] - 1;          // 512

    char* ws = (char*)d_ws;
    size_t off = 0;
    auto alloc = [&](size_t bytes) -> void* {
        void* p = ws + off;
        off += (bytes + 255) & ~(size_t)255;
        return p;
    };
    int*   cnt    = (int*)alloc((size_t)NN * 4);
    float* dinv   = (float*)alloc((size_t)NN * 4);
    int*   offs   = (int*)alloc((size_t)(NN + 1) * 4);
    int*   cursor = (int*)alloc((size_t)NN * 4);
    int*   bsums  = (int*)alloc(4096);
    int*   srt    = (int*)alloc((size_t)E * 4);
    float* G      = (float*)alloc((size_t)NN * HID * 4);
    float* H      = (float*)alloc((size_t)NN * HID * 4);
    float* G3     = (float*)alloc((size_t)NN * 2 * 4);
    unsigned short* Wt1_hi = (unsigned short*)alloc((size_t)IN_DIM * HID * 2);
    unsigned short* Wt1_lo = (unsigned short*)alloc((size_t)IN_DIM * HID * 2);
    unsigned short* Wt2_hi = (unsigned short*)alloc((size_t)HID * HID * 2);
    unsigned short* Wt2_lo = (unsigned short*)alloc((size_t)HID * HID * 2);

    (void)n_in; (void)out_size; (void)ws_size;

    hipMemsetAsync(cnt, 0, (size_t)NN * 4, stream);
    hist_kernel<<<2048, 256, 0, stream>>>(ei, cnt, E);
    dinv_kernel<<<(NN + 255) / 256, 256, 0, stream>>>(cnt, dinv, NN);

    int nb = (NN + 4095) / 4096;
    scan1_kernel<<<nb, 256, 0, stream>>>(cnt, offs, bsums, NN);
    scan2_kernel<<<1, 64, 0, stream>>>(bsums, offs, nb, NN);
    scan3_kernel<<<(NN + 255) / 256, 256, 0, stream>>>(bsums, offs, cursor, NN);
    scatter_kernel<<<2048, 256, 0, stream>>>(ei, cursor, srt, E);

    wt_prep<<<(IN_DIM * HID + 255) / 256, 256, 0, stream>>>(W1, Wt1_hi, Wt1_lo, IN_DIM);
    wt_prep<<<(HID * HID + 255) / 256, 256, 0, stream>>>(W2, Wt2_hi, Wt2_lo, HID);

    int gblocks = (NN + 127) / 128;
    int agg_blocks = (NN * 64 + 255) / 256;

    // layer 1
    gemm_mfma<768><<<gblocks, 256, 0, stream>>>(x, Wt1_hi, Wt1_lo, dinv, G, NN);
    aggregate_kernel<<<agg_blocks, 256, 0, stream>>>(G, offs, srt, dinv, b1, H, NN, 1);
    // layer 2
    gemm_mfma<128><<<gblocks, 256, 0, stream>>>(H, Wt2_hi, Wt2_lo, dinv, G, NN);
    aggregate_kernel<<<agg_blocks, 256, 0, stream>>>(G, offs, srt, dinv, b2, H, NN, 1);
    // layer 3
    gemm_c2_kernel<<<agg_blocks, 256, 0, stream>>>(H, Wc, dinv, G3, NN);
    final_kernel<<<NG, 64, 0, stream>>>(G3, ptr, offs, srt, dinv, bc, out, NG);
}